// Round 1
// baseline (272.745 us; speedup 1.0000x reference)
//
#include <hip/hip_runtime.h>

// GraphSAGE encoder: N=100000, E=1600000, D=64. fp32 in/out, bf16 internal.
// relu(Wl@mean(x) + Wr@x + b) == relu(mean(Wl@x) + (Wr@x + b))  [linearity]
// Round-10: (1) binA+binB two-phase CSR build replaced by single-pass direct
// scatter (pos = atomicAdd(&cnt[dst],1); colp[dst*64+pos]=src) -- contention
// is negligible at deg~16 over 100K counters, sum is order-independent, and
// the 8MB bucketData round-trip + 3.2M LDS atomics disappear. (2) that bin
// pass is fused (block-specialized) with the independent layer-1 transform so
// xform hides under the edge-list pass. (3) k_aggr's gather loops are fully
// unrolled with per-slot exec-mask predication (masked lanes issue no memory
// op -> no wasted BW) to raise memory-level parallelism: the y-table is
// L3-resident so aggr is latency-bound, not BW-bound.
//   k_bin_xf   : [blocks 0..NBIN)   edge scatter -> cnt/colp (one pass)
//                [blocks NBIN..end) y1||z1 = bf16(x) @ bf16([W1l;W1r])^T
//   k_aggr     : h = relu(mean_nbr(y) + z) in-place on z, all bf16 rows
//   k_xform_b16: y2||z2 = h1 @ bf16([W2l;W2r])^T (in-place z)
//   k_out      : logits = h2 @ Wout^T + bout; log_softmax -> d_out (fp32)

#define TB 256
#define NBIN 256   // edge-scatter blocks in k_bin_xf
#define XFB 512    // xform blocks in k_bin_xf

typedef __attribute__((ext_vector_type(8))) short bf16x8;
typedef __attribute__((ext_vector_type(4))) float f32x4;
typedef __attribute__((ext_vector_type(2))) float f32x2;

__device__ __forceinline__ unsigned short bf16c(float f) {
  union { float f; unsigned u; } v; v.f = f;
  unsigned r = (v.u + 0x7FFFu + ((v.u >> 16) & 1u)) >> 16;  // RNE
  return (unsigned short)r;
}

__device__ __forceinline__ bf16x8 ld_bf8(const float* p) {
  float4 a = *(const float4*)p;
  float4 b = *(const float4*)(p + 4);
  bf16x8 r;
  r[0] = bf16c(a.x); r[1] = bf16c(a.y); r[2] = bf16c(a.z); r[3] = bf16c(a.w);
  r[4] = bf16c(b.x); r[5] = bf16c(b.y); r[6] = bf16c(b.z); r[7] = bf16c(b.w);
  return r;
}

__device__ __forceinline__ float bflo(unsigned u) { return __uint_as_float(u << 16); }
__device__ __forceinline__ float bfhi(unsigned u) { return __uint_as_float(u & 0xFFFF0000u); }
__device__ __forceinline__ unsigned bfpk(float lo, float hi) {
  return (unsigned)bf16c(lo) | ((unsigned)bf16c(hi) << 16);
}

// ---- fused: edge scatter (blocks < NBIN) || layer-1 transform (the rest).
__global__ __launch_bounds__(256) void k_bin_xf(
    const int* __restrict__ ei, int E,
    int* __restrict__ cnt, int* __restrict__ colp,
    const float* __restrict__ xin, const float* __restrict__ Wl,
    const float* __restrict__ Wr, const float* __restrict__ bl,
    unsigned short* __restrict__ y, unsigned short* __restrict__ zout, int n) {
  if (blockIdx.x < NBIN) {
    // ---- edge scatter: cnt[dst]++ (exact degree), colp[dst*64+pos]=src.
    __shared__ int s_nz;
    if (threadIdx.x == 0) s_nz = 0;
    __syncthreads();
    int nz = 0;
    for (int i = threadIdx.x; i < 2048; i += TB) nz |= ei[2 * i + 1];
    if (nz) atomicOr(&s_nz, 1);
    __syncthreads();
    bool m64 = (s_nz == 0);  // int64 layout
    int bb = blockIdx.x;
    if (m64) {
      // 2 edges per iteration via int4 loads (e0 forced even for alignment).
      long long e0 = ((long long)E * bb / NBIN) & ~1LL;
      long long e1 = ((long long)E * (bb + 1) / NBIN) & ~1LL;
      if (bb == NBIN - 1) e1 = E;
      for (long long e = e0 + (long long)threadIdx.x * 2; e < e1; e += TB * 2) {
        int4 sp = *(const int4*)(ei + (e << 1));                  // src[e],src[e+1]
        int4 dp = *(const int4*)(ei + (((long long)E + e) << 1)); // dst[e],dst[e+1]
        int pos0 = atomicAdd(&cnt[dp.x], 1);
        if (pos0 < 64) colp[((size_t)dp.x << 6) + pos0] = sp.x;
        if (e + 1 < e1) {
          int pos1 = atomicAdd(&cnt[dp.z], 1);
          if (pos1 < 64) colp[((size_t)dp.z << 6) + pos1] = sp.z;
        }
      }
    } else {
      long long e0 = (long long)E * bb / NBIN;
      long long e1 = (long long)E * (bb + 1) / NBIN;
      for (long long e = e0 + threadIdx.x; e < e1; e += TB) {
        int src = ei[e];
        int dst = ei[(long long)E + e];
        int pos = atomicAdd(&cnt[dst], 1);
        if (pos < 64) colp[((size_t)dst << 6) + pos] = src;
      }
    }
    return;
  }

  // ---- layer-1 transform: y||z = bf16(x fp32) @ bf16([Wl;Wr])^T; y,z bf16.
  // Wave = 16-node tile, grid-stride. D layout (m89): feat=lane&15, node=quad*4+reg.
  int lane = threadIdx.x & 63;
  int quad = lane >> 4, m = lane & 15;
  int w0 = ((blockIdx.x - NBIN) * TB + threadIdx.x) >> 6;
  int nw = (XFB * TB) >> 6;

  bf16x8 bfrag[8][2];
  float bias[4];
#pragma unroll
  for (int t = 0; t < 8; ++t) {
    const float* W = (t < 4) ? Wl : Wr;
    int row = (t & 3) * 16 + m;
#pragma unroll
    for (int s = 0; s < 2; ++s)
      bfrag[t][s] = ld_bf8(W + row * 64 + s * 32 + quad * 8);
  }
#pragma unroll
  for (int t = 0; t < 4; ++t) bias[t] = bl[t * 16 + m];

  int nT = (n + 15) >> 4;
  for (int tile = w0; tile < nT; tile += nw) {
    int node0 = tile << 4;
    int mrow = node0 + m;
    if (mrow >= n) mrow = n - 1;
    const float* xr = xin + (size_t)mrow * 64;
    bf16x8 a0 = ld_bf8(xr + quad * 8);
    bf16x8 a1 = ld_bf8(xr + 32 + quad * 8);

    f32x4 acc[8];
#pragma unroll
    for (int t = 0; t < 8; ++t) {
      f32x4 z4 = {0.f, 0.f, 0.f, 0.f};
      z4 = __builtin_amdgcn_mfma_f32_16x16x32_bf16(a0, bfrag[t][0], z4, 0, 0, 0);
      acc[t] = __builtin_amdgcn_mfma_f32_16x16x32_bf16(a1, bfrag[t][1], z4, 0, 0, 0);
    }

#pragma unroll
    for (int r = 0; r < 4; ++r) {
      int node = node0 + quad * 4 + r;
      if (node >= n) break;
      size_t rb = (size_t)node * 64 + m;
#pragma unroll
      for (int t = 0; t < 4; ++t) y[rb + t * 16] = bf16c(acc[t][r]);
#pragma unroll
      for (int t = 0; t < 4; ++t) zout[rb + t * 16] = bf16c(acc[t + 4][r] + bias[t]);
    }
  }
}

// ---- layer-2 transform: input h1 is bf16 -> A-fragments load directly.
__global__ __launch_bounds__(256) void k_xform_b16(
    const unsigned short* zin, const float* __restrict__ Wl,
    const float* __restrict__ Wr, const float* __restrict__ bl,
    unsigned short* __restrict__ y, unsigned short* zout, int n) {
  int lane = threadIdx.x & 63;
  int quad = lane >> 4, m = lane & 15;
  int w0 = (blockIdx.x * blockDim.x + threadIdx.x) >> 6;
  int nw = (gridDim.x * blockDim.x) >> 6;

  bf16x8 bfrag[8][2];
  float bias[4];
#pragma unroll
  for (int t = 0; t < 8; ++t) {
    const float* W = (t < 4) ? Wl : Wr;
    int row = (t & 3) * 16 + m;
#pragma unroll
    for (int s = 0; s < 2; ++s)
      bfrag[t][s] = ld_bf8(W + row * 64 + s * 32 + quad * 8);
  }
#pragma unroll
  for (int t = 0; t < 4; ++t) bias[t] = bl[t * 16 + m];

  int nT = (n + 15) >> 4;
  for (int tile = w0; tile < nT; tile += nw) {
    int node0 = tile << 4;
    int mrow = node0 + m;
    if (mrow >= n) mrow = n - 1;
    const unsigned short* xr = zin + (size_t)mrow * 64;
    bf16x8 a0 = *(const bf16x8*)(xr + quad * 8);
    bf16x8 a1 = *(const bf16x8*)(xr + 32 + quad * 8);

    f32x4 acc[8];
#pragma unroll
    for (int t = 0; t < 8; ++t) {
      f32x4 z4 = {0.f, 0.f, 0.f, 0.f};
      z4 = __builtin_amdgcn_mfma_f32_16x16x32_bf16(a0, bfrag[t][0], z4, 0, 0, 0);
      acc[t] = __builtin_amdgcn_mfma_f32_16x16x32_bf16(a1, bfrag[t][1], z4, 0, 0, 0);
    }

#pragma unroll
    for (int r = 0; r < 4; ++r) {
      int node = node0 + quad * 4 + r;
      if (node >= n) break;
      size_t rb = (size_t)node * 64 + m;
#pragma unroll
      for (int t = 0; t < 4; ++t) y[rb + t * 16] = bf16c(acc[t][r]);
#pragma unroll
      for (int t = 0; t < 4; ++t) zout[rb + t * 16] = bf16c(acc[t + 4][r] + bias[t]);
    }
  }
}

// ---- aggregate: z[node] = relu(mean_nbr(y) + z[node]); y,z bf16 rows (128B).
// 4 nodes/wave: 16-lane groups; sub picks row of a slot pair; 8 lanes x uint4
// = one full row. Slots 0..31 fully unrolled with per-slot predication
// (masked lanes issue no memory op) -> up to 16 independent gathers in flight
// per wave. Rare slots 32..63 keep the dynamic path.
__global__ __launch_bounds__(256) void k_aggr(
    const unsigned short* __restrict__ yb, const int* __restrict__ cnt,
    const int* __restrict__ colp, unsigned short* zio, int n) {
  const unsigned int* y = (const unsigned int*)yb;  // 2 bf16 per u32; row = 32 u32
  int lane = threadIdx.x & 63;
  int wv = (blockIdx.x * blockDim.x + threadIdx.x) >> 6;
  int g16 = lane & 48;       // group base lane
  int lig = lane & 15;       // lane in group
  int sub = lig >> 3;        // which row of the current slot pair
  int fo = (lig & 7) * 4;    // u32 offset in row

  int node = (wv << 2) + (g16 >> 4);
  bool act = node < n;
  int cn = act ? node : 0;
  int deg = cnt[cn];
  int jcap = deg < 64 ? deg : 64;
  size_t crow = (size_t)cn << 6;
  int cidxA = colp[crow + lig];
  int cidxB = colp[crow + 16 + lig];

  int wmax = jcap;
  wmax = max(wmax, __shfl_xor(wmax, 16, 64));
  wmax = max(wmax, __shfl_xor(wmax, 32, 64));

  f32x2 acc[4];
#pragma unroll
  for (int k = 0; k < 4; ++k) acc[k] = (f32x2){0.f, 0.f};

#define ACCUM(U)                                             \
  do {                                                       \
    acc[0] += (f32x2){bflo((U).x), bfhi((U).x)};             \
    acc[1] += (f32x2){bflo((U).y), bfhi((U).y)};             \
    acc[2] += (f32x2){bflo((U).z), bfhi((U).z)};             \
    acc[3] += (f32x2){bflo((U).w), bfhi((U).w)};             \
  } while (0)

  // slots 0..15: full unroll, predicated loads (no BW cost for masked lanes)
#pragma unroll
  for (int s = 0; s < 16; s += 2) {
    int slot = s + sub;
    int c = __shfl(cidxA, g16 | slot, 64);
    if (slot < jcap) {
      uint4 v = *(const uint4*)(y + ((size_t)c << 5) + fo);
      ACCUM(v);
    }
  }
  if (wmax > 16) {  // slots 16..31: full unroll, predicated
#pragma unroll
    for (int s = 0; s < 16; s += 2) {
      int slot = s + sub;
      int c = __shfl(cidxB, g16 | slot, 64);
      if (slot + 16 < jcap) {
        uint4 v = *(const uint4*)(y + ((size_t)c << 5) + fo);
        ACCUM(v);
      }
    }
  }
  if (wmax > 32) {  // rare: slots 32..63
    int cidxC = colp[crow + 32 + lig];
    int cidxD = colp[crow + 48 + lig];
    {
      int lim = (wmax < 48 ? wmax : 48) - 32;
      for (int s = 0; s < lim; s += 2) {
        int slot = s + sub;
        int c = __shfl(cidxC, g16 | slot, 64);
        if (slot + 32 < jcap) {
          uint4 v = *(const uint4*)(y + ((size_t)c << 5) + fo);
          ACCUM(v);
        }
      }
    }
    if (wmax > 48) {
      int lim = wmax - 48;
      for (int s = 0; s < lim; s += 2) {
        int slot = s + sub;
        int c = __shfl(cidxD, g16 | slot, 64);
        if (slot + 48 < jcap) {
          uint4 v = *(const uint4*)(y + ((size_t)c << 5) + fo);
          ACCUM(v);
        }
      }
    }
  }
#undef ACCUM

#pragma unroll
  for (int k = 0; k < 4; ++k) {
    acc[k].x += __shfl_xor(acc[k].x, 8, 64);
    acc[k].y += __shfl_xor(acc[k].y, 8, 64);
  }

  if (act && sub == 0) {  // 8 lanes/group: lane owns u32s fo..fo+3 = feats 2fo..2fo+7
    float inv = (deg > 0) ? 1.0f / (float)deg : 0.f;
    unsigned int* zp = (unsigned int*)(zio + ((size_t)node << 6)) + fo;
    uint4 zv = *(uint4*)zp;
    zv.x = bfpk(fmaxf(fmaf(acc[0].x, inv, bflo(zv.x)), 0.f),
                fmaxf(fmaf(acc[0].y, inv, bfhi(zv.x)), 0.f));
    zv.y = bfpk(fmaxf(fmaf(acc[1].x, inv, bflo(zv.y)), 0.f),
                fmaxf(fmaf(acc[1].y, inv, bfhi(zv.y)), 0.f));
    zv.z = bfpk(fmaxf(fmaf(acc[2].x, inv, bflo(zv.z)), 0.f),
                fmaxf(fmaf(acc[2].y, inv, bfhi(zv.z)), 0.f));
    zv.w = bfpk(fmaxf(fmaf(acc[3].x, inv, bflo(zv.w)), 0.f),
                fmaxf(fmaf(acc[3].y, inv, bfhi(zv.w)), 0.f));
    *(uint4*)zp = zv;
  }
}

// ---- head: logits = h2(bf16) @ bf16(Wout)^T + bout; log_softmax -> fp32 out.
__global__ __launch_bounds__(256) void k_out(
    const unsigned short* __restrict__ h, const float* __restrict__ Wo,
    const float* __restrict__ bo, float* __restrict__ out, int n) {
  int lane = threadIdx.x & 63;
  int quad = lane >> 4, m = lane & 15;
  int w0 = (blockIdx.x * blockDim.x + threadIdx.x) >> 6;
  int nw = (gridDim.x * blockDim.x) >> 6;

  bf16x8 bfrag[4][2];
  float bias[4];
#pragma unroll
  for (int t = 0; t < 4; ++t) {
    int row = t * 16 + m;
#pragma unroll
    for (int s = 0; s < 2; ++s)
      bfrag[t][s] = ld_bf8(Wo + row * 64 + s * 32 + quad * 8);
    bias[t] = bo[t * 16 + m];
  }

  int nT = (n + 15) >> 4;
  for (int tile = w0; tile < nT; tile += nw) {
    int node0 = tile << 4;
    int mrow = node0 + m;
    if (mrow >= n) mrow = n - 1;
    const unsigned short* xr = h + (size_t)mrow * 64;
    bf16x8 a0 = *(const bf16x8*)(xr + quad * 8);
    bf16x8 a1 = *(const bf16x8*)(xr + 32 + quad * 8);

    f32x4 acc[4];
#pragma unroll
    for (int t = 0; t < 4; ++t) {
      f32x4 z4 = {0.f, 0.f, 0.f, 0.f};
      z4 = __builtin_amdgcn_mfma_f32_16x16x32_bf16(a0, bfrag[t][0], z4, 0, 0, 0);
      acc[t] = __builtin_amdgcn_mfma_f32_16x16x32_bf16(a1, bfrag[t][1], z4, 0, 0, 0);
    }

#pragma unroll
    for (int r = 0; r < 4; ++r) {
      int node = node0 + quad * 4 + r;
      if (node >= n) break;
      float l0 = acc[0][r] + bias[0];
      float l1 = acc[1][r] + bias[1];
      float l2 = acc[2][r] + bias[2];
      float l3 = acc[3][r] + bias[3];
      float mx = fmaxf(fmaxf(l0, l1), fmaxf(l2, l3));
#pragma unroll
      for (int off = 1; off <= 8; off <<= 1) mx = fmaxf(mx, __shfl_xor(mx, off, 64));
      float s = expf(l0 - mx) + expf(l1 - mx) + expf(l2 - mx) + expf(l3 - mx);
#pragma unroll
      for (int off = 1; off <= 8; off <<= 1) s += __shfl_xor(s, off, 64);
      float ls = logf(s);
      size_t rb = (size_t)node * 64 + m;
      out[rb + 0]  = l0 - mx - ls;
      out[rb + 16] = l1 - mx - ls;
      out[rb + 32] = l2 - mx - ls;
      out[rb + 48] = l3 - mx - ls;
    }
  }
}

extern "C" void kernel_launch(void* const* d_in, const int* in_sizes, int n_in,
                              void* d_out, int out_size, void* d_ws, size_t ws_size,
                              hipStream_t stream) {
  const float* x    = (const float*)d_in[0];
  const int*   ei   = (const int*)d_in[1];
  const float* W1l  = (const float*)d_in[2];
  const float* b1l  = (const float*)d_in[3];
  const float* W1r  = (const float*)d_in[4];
  const float* W2l  = (const float*)d_in[5];
  const float* b2l  = (const float*)d_in[6];
  const float* W2r  = (const float*)d_in[7];
  const float* Wout = (const float*)d_in[8];
  const float* bout = (const float*)d_in[9];
  int N = in_sizes[0] / 64;
  int E = in_sizes[1] / 2;
  int NB = (N + 127) >> 7;  // only for padded carve sizes

  char* p = (char*)d_ws;
  auto carve = [&](size_t bytes) {
    char* r = p;
    p += (bytes + 255) & ~(size_t)255;
    return r;
  };
  int* cnt           = (int*)carve((size_t)NB * 128 * 4);        // padded >= N
  int* colp          = (int*)carve((size_t)NB * 128 * 64 * 4);   // padded
  unsigned short* y  = (unsigned short*)carve((size_t)N * 64 * 2);
  unsigned short* z  = (unsigned short*)carve((size_t)N * 64 * 2);

  hipMemsetAsync(cnt, 0, (size_t)N * 4, stream);

  int aggr_blocks = (N + 15) / 16;  // 4 nodes/wave, 4 waves/block
  // edge scatter || layer-1 transform (independent -> one fused launch)
  k_bin_xf<<<NBIN + XFB, TB, 0, stream>>>(ei, E, cnt, colp, x, W1l, W1r, b1l, y, z, N);
  k_aggr<<<aggr_blocks, TB, 0, stream>>>(y, cnt, colp, z, N);  // z = h1 (bf16)
  // layer 2 (reads z in place; y buffer reused)
  k_xform_b16<<<XFB, TB, 0, stream>>>(z, W2l, W2r, b2l, y, z, N);
  k_aggr<<<aggr_blocks, TB, 0, stream>>>(y, cnt, colp, z, N);  // z = h2 (bf16)
  // head
  k_out<<<XFB, TB, 0, stream>>>(z, Wout, bout, (float*)d_out, N);
}

// Round 3
// 243.435 us; speedup vs baseline: 1.1204x; 1.1204x over previous
//
#include <hip/hip_runtime.h>

// GraphSAGE encoder: N=100000, E=1600000, D=64. fp32 in/out, bf16 internal.
// relu(Wl@mean(x) + Wr@x + b) == relu(mean(Wl@x) + (Wr@x + b))  [linearity]
// Round-12: resubmit of round-11 (bench infra failed twice; no profile).
// Round-10's single-pass scatter CSR build REGRESSED (100us, 122MB writes:
// random 4B stores -> 16x line amplification + dependent atomic chain).
// Two-phase bucketed build (bucket-local writes, LDS atomics) + binA||xform1
// block-specialized fusion at 256-thr blocks (88 VGPR -> 5 blocks/CU).
// bucketData no longer aliases z (xform1 writes z concurrently with binA).
//   k_binA_xf  : [blocks 0..NBINA)  bin edges into 128-node buckets
//                [blocks NBINA..)   y1||z1 = bf16(x) @ bf16([W1l;W1r])^T
//   k_binB     : per-bucket padded-CSR slice in LDS (32KB), streamed coalesced
//   k_aggr     : h = relu(mean_nbr(y) + z) in-place on z, all bf16 rows
//   k_xform_b16: y2||z2 = h1 @ bf16([W2l;W2r])^T (in-place z)
//   k_out      : logits = h2 @ Wout^T + bout; log_softmax -> d_out (fp32)

#define TB 256
#define NBINA 256  // bin blocks in k_binA_xf
#define XFB 512    // xform blocks in k_binA_xf
#define CAPB 2560  // slots per 128-node bucket: mean 2048, +11 sigma (Poisson)

typedef __attribute__((ext_vector_type(8))) short bf16x8;
typedef __attribute__((ext_vector_type(4))) float f32x4;
typedef __attribute__((ext_vector_type(2))) float f32x2;

__device__ __forceinline__ unsigned short bf16c(float f) {
  union { float f; unsigned u; } v; v.f = f;
  unsigned r = (v.u + 0x7FFFu + ((v.u >> 16) & 1u)) >> 16;  // RNE
  return (unsigned short)r;
}

__device__ __forceinline__ bf16x8 ld_bf8(const float* p) {
  float4 a = *(const float4*)p;
  float4 b = *(const float4*)(p + 4);
  bf16x8 r;
  r[0] = bf16c(a.x); r[1] = bf16c(a.y); r[2] = bf16c(a.z); r[3] = bf16c(a.w);
  r[4] = bf16c(b.x); r[5] = bf16c(b.y); r[6] = bf16c(b.z); r[7] = bf16c(b.w);
  return r;
}

__device__ __forceinline__ float bflo(unsigned u) { return __uint_as_float(u << 16); }
__device__ __forceinline__ float bfhi(unsigned u) { return __uint_as_float(u & 0xFFFF0000u); }
__device__ __forceinline__ unsigned bfpk(float lo, float hi) {
  return (unsigned)bf16c(lo) | ((unsigned)bf16c(hi) << 16);
}

// ---- fused: binA (blocks < NBINA) || layer-1 transform (the rest).
__global__ __launch_bounds__(256) void k_binA_xf(
    const int* __restrict__ ei, int E,
    int* __restrict__ bucket_fill, unsigned int* __restrict__ bucketData, int NB,
    const float* __restrict__ xin, const float* __restrict__ Wl,
    const float* __restrict__ Wr, const float* __restrict__ bl,
    unsigned short* __restrict__ y, unsigned short* __restrict__ zout, int n) {
  if (blockIdx.x < NBINA) {
    // ---- binA: histogram buckets, reserve per-(block,bucket) regions, place.
    __shared__ int hist[1024];
    __shared__ int base[1024];
    __shared__ int s_nz;
    if (threadIdx.x == 0) s_nz = 0;
    for (int i = threadIdx.x; i < NB; i += TB) hist[i] = 0;
    __syncthreads();
    int nz = 0;
    for (int i = threadIdx.x; i < 2048; i += TB) nz |= ei[2 * i + 1];
    if (nz) atomicOr(&s_nz, 1);
    __syncthreads();
    bool m64 = (s_nz == 0);  // int64 layout
    int bb = blockIdx.x;

    long long e0 = (long long)E * bb / NBINA;
    long long e1 = (long long)E * (bb + 1) / NBINA;
    for (long long e = e0 + threadIdx.x; e < e1; e += TB) {
      int dst = m64 ? ((const int2*)ei)[(long long)E + e].x : ei[(long long)E + e];
      atomicAdd(&hist[dst >> 7], 1);
    }
    __syncthreads();
    for (int b = threadIdx.x; b < NB; b += TB) {
      int c = hist[b];
      base[b] = c ? atomicAdd(&bucket_fill[b], c) : 0;
      hist[b] = 0;
    }
    __syncthreads();
    for (long long e = e0 + threadIdx.x; e < e1; e += TB) {
      int src, dst;
      if (m64) {
        src = ((const int2*)ei)[e].x;
        dst = ((const int2*)ei)[(long long)E + e].x;
      } else {
        src = ei[e];
        dst = ei[(long long)E + e];
      }
      int b = dst >> 7;
      int pos = base[b] + atomicAdd(&hist[b], 1);
      if (pos < CAPB)
        bucketData[(size_t)b * CAPB + pos] =
            ((unsigned)(dst & 127) << 24) | (unsigned)src;
    }
    return;
  }

  // ---- layer-1 transform: y||z = bf16(x fp32) @ bf16([Wl;Wr])^T; y,z bf16.
  // Wave = 16-node tile, grid-stride. D layout (m89): feat=lane&15, node=quad*4+reg.
  int lane = threadIdx.x & 63;
  int quad = lane >> 4, m = lane & 15;
  int w0 = ((blockIdx.x - NBINA) * TB + threadIdx.x) >> 6;
  int nw = (XFB * TB) >> 6;

  bf16x8 bfrag[8][2];
  float bias[4];
#pragma unroll
  for (int t = 0; t < 8; ++t) {
    const float* W = (t < 4) ? Wl : Wr;
    int row = (t & 3) * 16 + m;
#pragma unroll
    for (int s = 0; s < 2; ++s)
      bfrag[t][s] = ld_bf8(W + row * 64 + s * 32 + quad * 8);
  }
#pragma unroll
  for (int t = 0; t < 4; ++t) bias[t] = bl[t * 16 + m];

  int nT = (n + 15) >> 4;
  for (int tile = w0; tile < nT; tile += nw) {
    int node0 = tile << 4;
    int mrow = node0 + m;
    if (mrow >= n) mrow = n - 1;
    const float* xr = xin + (size_t)mrow * 64;
    bf16x8 a0 = ld_bf8(xr + quad * 8);
    bf16x8 a1 = ld_bf8(xr + 32 + quad * 8);

    f32x4 acc[8];
#pragma unroll
    for (int t = 0; t < 8; ++t) {
      f32x4 z4 = {0.f, 0.f, 0.f, 0.f};
      z4 = __builtin_amdgcn_mfma_f32_16x16x32_bf16(a0, bfrag[t][0], z4, 0, 0, 0);
      acc[t] = __builtin_amdgcn_mfma_f32_16x16x32_bf16(a1, bfrag[t][1], z4, 0, 0, 0);
    }

#pragma unroll
    for (int r = 0; r < 4; ++r) {
      int node = node0 + quad * 4 + r;
      if (node >= n) break;
      size_t rb = (size_t)node * 64 + m;
#pragma unroll
      for (int t = 0; t < 4; ++t) y[rb + t * 16] = bf16c(acc[t][r]);
#pragma unroll
      for (int t = 0; t < 4; ++t) zout[rb + t * 16] = bf16c(acc[t + 4][r] + bias[t]);
    }
  }
}

// ---- phase B: build each bucket's padded-CSR slice in LDS, stream out coalesced.
__global__ __launch_bounds__(256) void k_binB(
    const unsigned int* __restrict__ bucketData, const int* __restrict__ bucket_fill,
    int* __restrict__ colp, int* __restrict__ cnt) {
  __shared__ unsigned int slice[128 * 64];  // 32 KB
  __shared__ int lcnt[128];
  int b = blockIdx.x;
  for (int i = threadIdx.x; i < 128; i += TB) lcnt[i] = 0;
  __syncthreads();
  int fcnt = bucket_fill[b];
  if (fcnt > CAPB) fcnt = CAPB;
  const unsigned int* bd = bucketData + (size_t)b * CAPB;
  for (int k = threadIdx.x; k < fcnt; k += TB) {
    unsigned int rec = bd[k];
    int dl = rec >> 24;
    int pos = atomicAdd(&lcnt[dl], 1);
    if (pos < 64) slice[(dl << 6) + pos] = rec & 0xFFFFFFu;
  }
  __syncthreads();
  size_t obase = (size_t)b * (128 * 64);
  for (int i = threadIdx.x * 4; i < 128 * 64; i += TB * 4) {
    *(uint4*)(colp + obase + i) = *(const uint4*)(slice + i);
  }
  int node0 = b << 7;
  for (int i = threadIdx.x; i < 128; i += TB) cnt[node0 + i] = lcnt[i];
}

// ---- layer-2 transform: input h1 is bf16 -> A-fragments load directly.
__global__ __launch_bounds__(256) void k_xform_b16(
    const unsigned short* zin, const float* __restrict__ Wl,
    const float* __restrict__ Wr, const float* __restrict__ bl,
    unsigned short* __restrict__ y, unsigned short* zout, int n) {
  int lane = threadIdx.x & 63;
  int quad = lane >> 4, m = lane & 15;
  int w0 = (blockIdx.x * blockDim.x + threadIdx.x) >> 6;
  int nw = (gridDim.x * blockDim.x) >> 6;

  bf16x8 bfrag[8][2];
  float bias[4];
#pragma unroll
  for (int t = 0; t < 8; ++t) {
    const float* W = (t < 4) ? Wl : Wr;
    int row = (t & 3) * 16 + m;
#pragma unroll
    for (int s = 0; s < 2; ++s)
      bfrag[t][s] = ld_bf8(W + row * 64 + s * 32 + quad * 8);
  }
#pragma unroll
  for (int t = 0; t < 4; ++t) bias[t] = bl[t * 16 + m];

  int nT = (n + 15) >> 4;
  for (int tile = w0; tile < nT; tile += nw) {
    int node0 = tile << 4;
    int mrow = node0 + m;
    if (mrow >= n) mrow = n - 1;
    const unsigned short* xr = zin + (size_t)mrow * 64;
    bf16x8 a0 = *(const bf16x8*)(xr + quad * 8);
    bf16x8 a1 = *(const bf16x8*)(xr + 32 + quad * 8);

    f32x4 acc[8];
#pragma unroll
    for (int t = 0; t < 8; ++t) {
      f32x4 z4 = {0.f, 0.f, 0.f, 0.f};
      z4 = __builtin_amdgcn_mfma_f32_16x16x32_bf16(a0, bfrag[t][0], z4, 0, 0, 0);
      acc[t] = __builtin_amdgcn_mfma_f32_16x16x32_bf16(a1, bfrag[t][1], z4, 0, 0, 0);
    }

#pragma unroll
    for (int r = 0; r < 4; ++r) {
      int node = node0 + quad * 4 + r;
      if (node >= n) break;
      size_t rb = (size_t)node * 64 + m;
#pragma unroll
      for (int t = 0; t < 4; ++t) y[rb + t * 16] = bf16c(acc[t][r]);
#pragma unroll
      for (int t = 0; t < 4; ++t) zout[rb + t * 16] = bf16c(acc[t + 4][r] + bias[t]);
    }
  }
}

// ---- aggregate: z[node] = relu(mean_nbr(y) + z[node]); y,z bf16 rows (128B).
// 4 nodes/wave: 16-lane groups; sub picks row of a slot pair; 8 lanes x uint4
// = one full row. Slots 0..31 fully unrolled with per-slot predication
// (masked lanes issue no memory op). Rare slots 32..63 keep the dynamic path.
__global__ __launch_bounds__(256) void k_aggr(
    const unsigned short* __restrict__ yb, const int* __restrict__ cnt,
    const int* __restrict__ colp, unsigned short* zio, int n) {
  const unsigned int* y = (const unsigned int*)yb;  // 2 bf16 per u32; row = 32 u32
  int lane = threadIdx.x & 63;
  int wv = (blockIdx.x * blockDim.x + threadIdx.x) >> 6;
  int g16 = lane & 48;       // group base lane
  int lig = lane & 15;       // lane in group
  int sub = lig >> 3;        // which row of the current slot pair
  int fo = (lig & 7) * 4;    // u32 offset in row

  int node = (wv << 2) + (g16 >> 4);
  bool act = node < n;
  int cn = act ? node : 0;
  int deg = cnt[cn];
  int jcap = deg < 64 ? deg : 64;
  size_t crow = (size_t)cn << 6;
  int cidxA = colp[crow + lig];
  int cidxB = colp[crow + 16 + lig];

  int wmax = jcap;
  wmax = max(wmax, __shfl_xor(wmax, 16, 64));
  wmax = max(wmax, __shfl_xor(wmax, 32, 64));

  f32x2 acc[4];
#pragma unroll
  for (int k = 0; k < 4; ++k) acc[k] = (f32x2){0.f, 0.f};

#define ACCUM(U)                                             \
  do {                                                       \
    acc[0] += (f32x2){bflo((U).x), bfhi((U).x)};             \
    acc[1] += (f32x2){bflo((U).y), bfhi((U).y)};             \
    acc[2] += (f32x2){bflo((U).z), bfhi((U).z)};             \
    acc[3] += (f32x2){bflo((U).w), bfhi((U).w)};             \
  } while (0)

  // slots 0..15: full unroll, predicated loads (no BW cost for masked lanes)
#pragma unroll
  for (int s = 0; s < 16; s += 2) {
    int slot = s + sub;
    int c = __shfl(cidxA, g16 | slot, 64);
    if (slot < jcap) {
      uint4 v = *(const uint4*)(y + ((size_t)c << 5) + fo);
      ACCUM(v);
    }
  }
  if (wmax > 16) {  // slots 16..31: full unroll, predicated
#pragma unroll
    for (int s = 0; s < 16; s += 2) {
      int slot = s + sub;
      int c = __shfl(cidxB, g16 | slot, 64);
      if (slot + 16 < jcap) {
        uint4 v = *(const uint4*)(y + ((size_t)c << 5) + fo);
        ACCUM(v);
      }
    }
  }
  if (wmax > 32) {  // rare: slots 32..63
    int cidxC = colp[crow + 32 + lig];
    int cidxD = colp[crow + 48 + lig];
    {
      int lim = (wmax < 48 ? wmax : 48) - 32;
      for (int s = 0; s < lim; s += 2) {
        int slot = s + sub;
        int c = __shfl(cidxC, g16 | slot, 64);
        if (slot + 32 < jcap) {
          uint4 v = *(const uint4*)(y + ((size_t)c << 5) + fo);
          ACCUM(v);
        }
      }
    }
    if (wmax > 48) {
      int lim = wmax - 48;
      for (int s = 0; s < lim; s += 2) {
        int slot = s + sub;
        int c = __shfl(cidxD, g16 | slot, 64);
        if (slot + 48 < jcap) {
          uint4 v = *(const uint4*)(y + ((size_t)c << 5) + fo);
          ACCUM(v);
        }
      }
    }
  }
#undef ACCUM

#pragma unroll
  for (int k = 0; k < 4; ++k) {
    acc[k].x += __shfl_xor(acc[k].x, 8, 64);
    acc[k].y += __shfl_xor(acc[k].y, 8, 64);
  }

  if (act && sub == 0) {  // 8 lanes/group: lane owns u32s fo..fo+3 = feats 2fo..2fo+7
    float inv = (deg > 0) ? 1.0f / (float)deg : 0.f;
    unsigned int* zp = (unsigned int*)(zio + ((size_t)node << 6)) + fo;
    uint4 zv = *(uint4*)zp;
    zv.x = bfpk(fmaxf(fmaf(acc[0].x, inv, bflo(zv.x)), 0.f),
                fmaxf(fmaf(acc[0].y, inv, bfhi(zv.x)), 0.f));
    zv.y = bfpk(fmaxf(fmaf(acc[1].x, inv, bflo(zv.y)), 0.f),
                fmaxf(fmaf(acc[1].y, inv, bfhi(zv.y)), 0.f));
    zv.z = bfpk(fmaxf(fmaf(acc[2].x, inv, bflo(zv.z)), 0.f),
                fmaxf(fmaf(acc[2].y, inv, bfhi(zv.z)), 0.f));
    zv.w = bfpk(fmaxf(fmaf(acc[3].x, inv, bflo(zv.w)), 0.f),
                fmaxf(fmaf(acc[3].y, inv, bfhi(zv.w)), 0.f));
    *(uint4*)zp = zv;
  }
}

// ---- head: logits = h2(bf16) @ bf16(Wout)^T + bout; log_softmax -> fp32 out.
__global__ __launch_bounds__(256) void k_out(
    const unsigned short* __restrict__ h, const float* __restrict__ Wo,
    const float* __restrict__ bo, float* __restrict__ out, int n) {
  int lane = threadIdx.x & 63;
  int quad = lane >> 4, m = lane & 15;
  int w0 = (blockIdx.x * blockDim.x + threadIdx.x) >> 6;
  int nw = (gridDim.x * blockDim.x) >> 6;

  bf16x8 bfrag[4][2];
  float bias[4];
#pragma unroll
  for (int t = 0; t < 4; ++t) {
    int row = t * 16 + m;
#pragma unroll
    for (int s = 0; s < 2; ++s)
      bfrag[t][s] = ld_bf8(Wo + row * 64 + s * 32 + quad * 8);
    bias[t] = bo[t * 16 + m];
  }

  int nT = (n + 15) >> 4;
  for (int tile = w0; tile < nT; tile += nw) {
    int node0 = tile << 4;
    int mrow = node0 + m;
    if (mrow >= n) mrow = n - 1;
    const unsigned short* xr = h + (size_t)mrow * 64;
    bf16x8 a0 = *(const bf16x8*)(xr + quad * 8);
    bf16x8 a1 = *(const bf16x8*)(xr + 32 + quad * 8);

    f32x4 acc[4];
#pragma unroll
    for (int t = 0; t < 4; ++t) {
      f32x4 z4 = {0.f, 0.f, 0.f, 0.f};
      z4 = __builtin_amdgcn_mfma_f32_16x16x32_bf16(a0, bfrag[t][0], z4, 0, 0, 0);
      acc[t] = __builtin_amdgcn_mfma_f32_16x16x32_bf16(a1, bfrag[t][1], z4, 0, 0, 0);
    }

#pragma unroll
    for (int r = 0; r < 4; ++r) {
      int node = node0 + quad * 4 + r;
      if (node >= n) break;
      float l0 = acc[0][r] + bias[0];
      float l1 = acc[1][r] + bias[1];
      float l2 = acc[2][r] + bias[2];
      float l3 = acc[3][r] + bias[3];
      float mx = fmaxf(fmaxf(l0, l1), fmaxf(l2, l3));
#pragma unroll
      for (int off = 1; off <= 8; off <<= 1) mx = fmaxf(mx, __shfl_xor(mx, off, 64));
      float s = expf(l0 - mx) + expf(l1 - mx) + expf(l2 - mx) + expf(l3 - mx);
#pragma unroll
      for (int off = 1; off <= 8; off <<= 1) s += __shfl_xor(s, off, 64);
      float ls = logf(s);
      size_t rb = (size_t)node * 64 + m;
      out[rb + 0]  = l0 - mx - ls;
      out[rb + 16] = l1 - mx - ls;
      out[rb + 32] = l2 - mx - ls;
      out[rb + 48] = l3 - mx - ls;
    }
  }
}

extern "C" void kernel_launch(void* const* d_in, const int* in_sizes, int n_in,
                              void* d_out, int out_size, void* d_ws, size_t ws_size,
                              hipStream_t stream) {
  const float* x    = (const float*)d_in[0];
  const int*   ei   = (const int*)d_in[1];
  const float* W1l  = (const float*)d_in[2];
  const float* b1l  = (const float*)d_in[3];
  const float* W1r  = (const float*)d_in[4];
  const float* W2l  = (const float*)d_in[5];
  const float* b2l  = (const float*)d_in[6];
  const float* W2r  = (const float*)d_in[7];
  const float* Wout = (const float*)d_in[8];
  const float* bout = (const float*)d_in[9];
  int N = in_sizes[0] / 64;
  int E = in_sizes[1] / 2;
  int NB = (N + 127) >> 7;  // 128-node buckets; NB=782 <= 1024 (binA LDS)

  char* p = (char*)d_ws;
  auto carve = [&](size_t bytes) {
    char* r = p;
    p += (bytes + 255) & ~(size_t)255;
    return r;
  };
  int* bucket_fill   = (int*)carve((size_t)NB * 4);
  int* cnt           = (int*)carve((size_t)NB * 128 * 4);        // padded
  int* colp          = (int*)carve((size_t)NB * 128 * 64 * 4);   // padded
  unsigned short* y  = (unsigned short*)carve((size_t)N * 64 * 2);
  unsigned short* z  = (unsigned short*)carve((size_t)N * 64 * 2);
  // bucketData gets its OWN carve (8 MB): xform1 writes z concurrently
  // with binA in the fused launch, so the old bucketData<->z alias is illegal.
  unsigned int* bucketData = (unsigned int*)carve((size_t)NB * CAPB * 4);

  hipMemsetAsync(bucket_fill, 0, (size_t)NB * 4, stream);

  int aggr_blocks = (N + 15) / 16;  // 4 nodes/wave, 4 waves/block
  // binA || layer-1 transform (independent -> one fused launch, co-resident)
  k_binA_xf<<<NBINA + XFB, TB, 0, stream>>>(ei, E, bucket_fill, bucketData, NB,
                                            x, W1l, W1r, b1l, y, z, N);
  k_binB<<<NB, TB, 0, stream>>>(bucketData, bucket_fill, colp, cnt);
  k_aggr<<<aggr_blocks, TB, 0, stream>>>(y, cnt, colp, z, N);  // z = h1 (bf16)
  // layer 2 (reads z in place; y buffer reused)
  k_xform_b16<<<XFB, TB, 0, stream>>>(z, W2l, W2r, b2l, y, z, N);
  k_aggr<<<aggr_blocks, TB, 0, stream>>>(y, cnt, colp, z, N);  // z = h2 (bf16)
  // head
  k_out<<<XFB, TB, 0, stream>>>(z, Wout, bout, (float*)d_out, N);
}

// Round 4
// 239.899 us; speedup vs baseline: 1.1369x; 1.0147x over previous
//
#include <hip/hip_runtime.h>

// GraphSAGE encoder: N=100000, E=1600000, D=64. fp32 in/out, bf16 internal.
// relu(Wl@mean(x) + Wr@x + b) == relu(mean(Wl@x) + (Wr@x + b))  [linearity]
// Round-13: binA's histogram pass eliminated via deterministic per-
// (bucket,block) cells: block bb owns 32 slots at bucketData[(b*256+bb)*32],
// placement uses only a block-local LDS counter -> ONE pass over the edge
// list (was two), zero global atomics, no memset. Cell overflow P(Poisson(8)
// >32) ~ 1e-12. binB drains cells thread-per-cell into the same LDS slice.
// (Round-12 counters: binA_xf 58us with Occ 14.6%/VALU 7%/HBM 16% -- pure
// latency-bound two-pass structure; this halves its memory work.)
//   k_binA_xf  : [blocks 0..NBINA)  single-pass edge binning into cells
//                [blocks NBINA..)   y1||z1 = bf16(x) @ bf16([W1l;W1r])^T
//   k_binB     : per-bucket padded-CSR slice in LDS (32KB), streamed coalesced
//   k_aggr     : h = relu(mean_nbr(y) + z) in-place on z, all bf16 rows
//   k_xform_b16: y2||z2 = h1 @ bf16([W2l;W2r])^T (in-place z)
//   k_out      : logits = h2 @ Wout^T + bout; log_softmax -> d_out (fp32)

#define TB 256
#define NBINA 256  // bin blocks (== TB so binB can go thread-per-cell)
#define XFB 512    // xform blocks in k_binA_xf
#define CAPC 32    // slots per (bucket,block) cell: mean 8, P(>32)~1e-12
#define NBPAD 1024

typedef __attribute__((ext_vector_type(8))) short bf16x8;
typedef __attribute__((ext_vector_type(4))) float f32x4;
typedef __attribute__((ext_vector_type(2))) float f32x2;

__device__ __forceinline__ unsigned short bf16c(float f) {
  union { float f; unsigned u; } v; v.f = f;
  unsigned r = (v.u + 0x7FFFu + ((v.u >> 16) & 1u)) >> 16;  // RNE
  return (unsigned short)r;
}

__device__ __forceinline__ bf16x8 ld_bf8(const float* p) {
  float4 a = *(const float4*)p;
  float4 b = *(const float4*)(p + 4);
  bf16x8 r;
  r[0] = bf16c(a.x); r[1] = bf16c(a.y); r[2] = bf16c(a.z); r[3] = bf16c(a.w);
  r[4] = bf16c(b.x); r[5] = bf16c(b.y); r[6] = bf16c(b.z); r[7] = bf16c(b.w);
  return r;
}

__device__ __forceinline__ float bflo(unsigned u) { return __uint_as_float(u << 16); }
__device__ __forceinline__ float bfhi(unsigned u) { return __uint_as_float(u & 0xFFFF0000u); }
__device__ __forceinline__ unsigned bfpk(float lo, float hi) {
  return (unsigned)bf16c(lo) | ((unsigned)bf16c(hi) << 16);
}

// ---- fused: single-pass binning (blocks < NBINA) || layer-1 transform.
__global__ __launch_bounds__(256) void k_binA_xf(
    const int* __restrict__ ei, int E,
    int* __restrict__ cellcnt, unsigned int* __restrict__ bucketData, int NB,
    const float* __restrict__ xin, const float* __restrict__ Wl,
    const float* __restrict__ Wr, const float* __restrict__ bl,
    unsigned short* __restrict__ y, unsigned short* __restrict__ zout, int n) {
  if (blockIdx.x < NBINA) {
    __shared__ int lcnt[NBPAD];
    __shared__ int s_nz;
    if (threadIdx.x == 0) s_nz = 0;
    for (int i = threadIdx.x; i < NBPAD; i += TB) lcnt[i] = 0;
    __syncthreads();
    int nz = 0;
    for (int i = threadIdx.x; i < 2048; i += TB) nz |= ei[2 * i + 1];
    if (nz) atomicOr(&s_nz, 1);
    __syncthreads();
    bool m64 = (s_nz == 0);  // int64 layout
    int bb = blockIdx.x;

    long long e0 = (long long)E * bb / NBINA;
    long long e1 = (long long)E * (bb + 1) / NBINA;
    for (long long e = e0 + threadIdx.x; e < e1; e += TB) {
      int src, dst;
      if (m64) {
        src = ((const int2*)ei)[e].x;
        dst = ((const int2*)ei)[(long long)E + e].x;
      } else {
        src = ei[e];
        dst = ei[(long long)E + e];
      }
      int b = dst >> 7;
      int pos = atomicAdd(&lcnt[b], 1);
      if (pos < CAPC)
        bucketData[((size_t)b * NBINA + bb) * CAPC + pos] =
            ((unsigned)(dst & 127) << 24) | (unsigned)src;
    }
    __syncthreads();
    // coalesced: block bb owns contiguous row cellcnt[bb*NBPAD + 0..NB)
    for (int b = threadIdx.x; b < NB; b += TB) cellcnt[bb * NBPAD + b] = lcnt[b];
    return;
  }

  // ---- layer-1 transform: y||z = bf16(x fp32) @ bf16([Wl;Wr])^T; y,z bf16.
  // Wave = 16-node tile, grid-stride. D layout (m89): feat=lane&15, node=quad*4+reg.
  int lane = threadIdx.x & 63;
  int quad = lane >> 4, m = lane & 15;
  int w0 = ((blockIdx.x - NBINA) * TB + threadIdx.x) >> 6;
  int nw = (XFB * TB) >> 6;

  bf16x8 bfrag[8][2];
  float bias[4];
#pragma unroll
  for (int t = 0; t < 8; ++t) {
    const float* W = (t < 4) ? Wl : Wr;
    int row = (t & 3) * 16 + m;
#pragma unroll
    for (int s = 0; s < 2; ++s)
      bfrag[t][s] = ld_bf8(W + row * 64 + s * 32 + quad * 8);
  }
#pragma unroll
  for (int t = 0; t < 4; ++t) bias[t] = bl[t * 16 + m];

  int nT = (n + 15) >> 4;
  for (int tile = w0; tile < nT; tile += nw) {
    int node0 = tile << 4;
    int mrow = node0 + m;
    if (mrow >= n) mrow = n - 1;
    const float* xr = xin + (size_t)mrow * 64;
    bf16x8 a0 = ld_bf8(xr + quad * 8);
    bf16x8 a1 = ld_bf8(xr + 32 + quad * 8);

    f32x4 acc[8];
#pragma unroll
    for (int t = 0; t < 8; ++t) {
      f32x4 z4 = {0.f, 0.f, 0.f, 0.f};
      z4 = __builtin_amdgcn_mfma_f32_16x16x32_bf16(a0, bfrag[t][0], z4, 0, 0, 0);
      acc[t] = __builtin_amdgcn_mfma_f32_16x16x32_bf16(a1, bfrag[t][1], z4, 0, 0, 0);
    }

#pragma unroll
    for (int r = 0; r < 4; ++r) {
      int node = node0 + quad * 4 + r;
      if (node >= n) break;
      size_t rb = (size_t)node * 64 + m;
#pragma unroll
      for (int t = 0; t < 4; ++t) y[rb + t * 16] = bf16c(acc[t][r]);
#pragma unroll
      for (int t = 0; t < 4; ++t) zout[rb + t * 16] = bf16c(acc[t + 4][r] + bias[t]);
    }
  }
}

// ---- phase B: drain cells thread-per-cell into the bucket's padded-CSR
// slice in LDS (32KB), stream out coalesced.
__global__ __launch_bounds__(256) void k_binB(
    const unsigned int* __restrict__ bucketData, const int* __restrict__ cellcnt,
    int* __restrict__ colp, int* __restrict__ cnt) {
  __shared__ unsigned int slice[128 * 64];  // 32 KB
  __shared__ int lcnt[128];
  int b = blockIdx.x;
  for (int i = threadIdx.x; i < 128; i += TB) lcnt[i] = 0;
  __syncthreads();
  // thread tid owns cell (b, tid): count in cellcnt[tid*NBPAD+b]
  int c = cellcnt[threadIdx.x * NBPAD + b];
  if (c > CAPC) c = CAPC;
  const unsigned int* cell = bucketData + ((size_t)b * NBINA + threadIdx.x) * CAPC;
  for (int k = 0; k < c; ++k) {
    unsigned int rec = cell[k];
    int dl = rec >> 24;
    int pos = atomicAdd(&lcnt[dl], 1);
    if (pos < 64) slice[(dl << 6) + pos] = rec & 0xFFFFFFu;
  }
  __syncthreads();
  size_t obase = (size_t)b * (128 * 64);
  for (int i = threadIdx.x * 4; i < 128 * 64; i += TB * 4) {
    *(uint4*)(colp + obase + i) = *(const uint4*)(slice + i);
  }
  int node0 = b << 7;
  for (int i = threadIdx.x; i < 128; i += TB) cnt[node0 + i] = lcnt[i];
}

// ---- layer-2 transform: input h1 is bf16 -> A-fragments load directly.
__global__ __launch_bounds__(256) void k_xform_b16(
    const unsigned short* zin, const float* __restrict__ Wl,
    const float* __restrict__ Wr, const float* __restrict__ bl,
    unsigned short* __restrict__ y, unsigned short* zout, int n) {
  int lane = threadIdx.x & 63;
  int quad = lane >> 4, m = lane & 15;
  int w0 = (blockIdx.x * blockDim.x + threadIdx.x) >> 6;
  int nw = (gridDim.x * blockDim.x) >> 6;

  bf16x8 bfrag[8][2];
  float bias[4];
#pragma unroll
  for (int t = 0; t < 8; ++t) {
    const float* W = (t < 4) ? Wl : Wr;
    int row = (t & 3) * 16 + m;
#pragma unroll
    for (int s = 0; s < 2; ++s)
      bfrag[t][s] = ld_bf8(W + row * 64 + s * 32 + quad * 8);
  }
#pragma unroll
  for (int t = 0; t < 4; ++t) bias[t] = bl[t * 16 + m];

  int nT = (n + 15) >> 4;
  for (int tile = w0; tile < nT; tile += nw) {
    int node0 = tile << 4;
    int mrow = node0 + m;
    if (mrow >= n) mrow = n - 1;
    const unsigned short* xr = zin + (size_t)mrow * 64;
    bf16x8 a0 = *(const bf16x8*)(xr + quad * 8);
    bf16x8 a1 = *(const bf16x8*)(xr + 32 + quad * 8);

    f32x4 acc[8];
#pragma unroll
    for (int t = 0; t < 8; ++t) {
      f32x4 z4 = {0.f, 0.f, 0.f, 0.f};
      z4 = __builtin_amdgcn_mfma_f32_16x16x32_bf16(a0, bfrag[t][0], z4, 0, 0, 0);
      acc[t] = __builtin_amdgcn_mfma_f32_16x16x32_bf16(a1, bfrag[t][1], z4, 0, 0, 0);
    }

#pragma unroll
    for (int r = 0; r < 4; ++r) {
      int node = node0 + quad * 4 + r;
      if (node >= n) break;
      size_t rb = (size_t)node * 64 + m;
#pragma unroll
      for (int t = 0; t < 4; ++t) y[rb + t * 16] = bf16c(acc[t][r]);
#pragma unroll
      for (int t = 0; t < 4; ++t) zout[rb + t * 16] = bf16c(acc[t + 4][r] + bias[t]);
    }
  }
}

// ---- aggregate: z[node] = relu(mean_nbr(y) + z[node]); y,z bf16 rows (128B).
// 4 nodes/wave: 16-lane groups; sub picks row of a slot pair; 8 lanes x uint4
// = one full row. Slots 0..31 fully unrolled with per-slot predication
// (masked lanes issue no memory op). Rare slots 32..63 keep the dynamic path.
__global__ __launch_bounds__(256) void k_aggr(
    const unsigned short* __restrict__ yb, const int* __restrict__ cnt,
    const int* __restrict__ colp, unsigned short* zio, int n) {
  const unsigned int* y = (const unsigned int*)yb;  // 2 bf16 per u32; row = 32 u32
  int lane = threadIdx.x & 63;
  int wv = (blockIdx.x * blockDim.x + threadIdx.x) >> 6;
  int g16 = lane & 48;       // group base lane
  int lig = lane & 15;       // lane in group
  int sub = lig >> 3;        // which row of the current slot pair
  int fo = (lig & 7) * 4;    // u32 offset in row

  int node = (wv << 2) + (g16 >> 4);
  bool act = node < n;
  int cn = act ? node : 0;
  int deg = cnt[cn];
  int jcap = deg < 64 ? deg : 64;
  size_t crow = (size_t)cn << 6;
  int cidxA = colp[crow + lig];
  int cidxB = colp[crow + 16 + lig];

  int wmax = jcap;
  wmax = max(wmax, __shfl_xor(wmax, 16, 64));
  wmax = max(wmax, __shfl_xor(wmax, 32, 64));

  f32x2 acc[4];
#pragma unroll
  for (int k = 0; k < 4; ++k) acc[k] = (f32x2){0.f, 0.f};

#define ACCUM(U)                                             \
  do {                                                       \
    acc[0] += (f32x2){bflo((U).x), bfhi((U).x)};             \
    acc[1] += (f32x2){bflo((U).y), bfhi((U).y)};             \
    acc[2] += (f32x2){bflo((U).z), bfhi((U).z)};             \
    acc[3] += (f32x2){bflo((U).w), bfhi((U).w)};             \
  } while (0)

  // slots 0..15: full unroll, predicated loads (no BW cost for masked lanes)
#pragma unroll
  for (int s = 0; s < 16; s += 2) {
    int slot = s + sub;
    int c = __shfl(cidxA, g16 | slot, 64);
    if (slot < jcap) {
      uint4 v = *(const uint4*)(y + ((size_t)c << 5) + fo);
      ACCUM(v);
    }
  }
  if (wmax > 16) {  // slots 16..31: full unroll, predicated
#pragma unroll
    for (int s = 0; s < 16; s += 2) {
      int slot = s + sub;
      int c = __shfl(cidxB, g16 | slot, 64);
      if (slot + 16 < jcap) {
        uint4 v = *(const uint4*)(y + ((size_t)c << 5) + fo);
        ACCUM(v);
      }
    }
  }
  if (wmax > 32) {  // rare: slots 32..63
    int cidxC = colp[crow + 32 + lig];
    int cidxD = colp[crow + 48 + lig];
    {
      int lim = (wmax < 48 ? wmax : 48) - 32;
      for (int s = 0; s < lim; s += 2) {
        int slot = s + sub;
        int c = __shfl(cidxC, g16 | slot, 64);
        if (slot + 32 < jcap) {
          uint4 v = *(const uint4*)(y + ((size_t)c << 5) + fo);
          ACCUM(v);
        }
      }
    }
    if (wmax > 48) {
      int lim = wmax - 48;
      for (int s = 0; s < lim; s += 2) {
        int slot = s + sub;
        int c = __shfl(cidxD, g16 | slot, 64);
        if (slot + 48 < jcap) {
          uint4 v = *(const uint4*)(y + ((size_t)c << 5) + fo);
          ACCUM(v);
        }
      }
    }
  }
#undef ACCUM

#pragma unroll
  for (int k = 0; k < 4; ++k) {
    acc[k].x += __shfl_xor(acc[k].x, 8, 64);
    acc[k].y += __shfl_xor(acc[k].y, 8, 64);
  }

  if (act && sub == 0) {  // 8 lanes/group: lane owns u32s fo..fo+3 = feats 2fo..2fo+7
    float inv = (deg > 0) ? 1.0f / (float)deg : 0.f;
    unsigned int* zp = (unsigned int*)(zio + ((size_t)node << 6)) + fo;
    uint4 zv = *(uint4*)zp;
    zv.x = bfpk(fmaxf(fmaf(acc[0].x, inv, bflo(zv.x)), 0.f),
                fmaxf(fmaf(acc[0].y, inv, bfhi(zv.x)), 0.f));
    zv.y = bfpk(fmaxf(fmaf(acc[1].x, inv, bflo(zv.y)), 0.f),
                fmaxf(fmaf(acc[1].y, inv, bfhi(zv.y)), 0.f));
    zv.z = bfpk(fmaxf(fmaf(acc[2].x, inv, bflo(zv.z)), 0.f),
                fmaxf(fmaf(acc[2].y, inv, bfhi(zv.z)), 0.f));
    zv.w = bfpk(fmaxf(fmaf(acc[3].x, inv, bflo(zv.w)), 0.f),
                fmaxf(fmaf(acc[3].y, inv, bfhi(zv.w)), 0.f));
    *(uint4*)zp = zv;
  }
}

// ---- head: logits = h2(bf16) @ bf16(Wout)^T + bout; log_softmax -> fp32 out.
__global__ __launch_bounds__(256) void k_out(
    const unsigned short* __restrict__ h, const float* __restrict__ Wo,
    const float* __restrict__ bo, float* __restrict__ out, int n) {
  int lane = threadIdx.x & 63;
  int quad = lane >> 4, m = lane & 15;
  int w0 = (blockIdx.x * blockDim.x + threadIdx.x) >> 6;
  int nw = (gridDim.x * blockDim.x) >> 6;

  bf16x8 bfrag[4][2];
  float bias[4];
#pragma unroll
  for (int t = 0; t < 4; ++t) {
    int row = t * 16 + m;
#pragma unroll
    for (int s = 0; s < 2; ++s)
      bfrag[t][s] = ld_bf8(Wo + row * 64 + s * 32 + quad * 8);
    bias[t] = bo[t * 16 + m];
  }

  int nT = (n + 15) >> 4;
  for (int tile = w0; tile < nT; tile += nw) {
    int node0 = tile << 4;
    int mrow = node0 + m;
    if (mrow >= n) mrow = n - 1;
    const unsigned short* xr = h + (size_t)mrow * 64;
    bf16x8 a0 = *(const bf16x8*)(xr + quad * 8);
    bf16x8 a1 = *(const bf16x8*)(xr + 32 + quad * 8);

    f32x4 acc[4];
#pragma unroll
    for (int t = 0; t < 4; ++t) {
      f32x4 z4 = {0.f, 0.f, 0.f, 0.f};
      z4 = __builtin_amdgcn_mfma_f32_16x16x32_bf16(a0, bfrag[t][0], z4, 0, 0, 0);
      acc[t] = __builtin_amdgcn_mfma_f32_16x16x32_bf16(a1, bfrag[t][1], z4, 0, 0, 0);
    }

#pragma unroll
    for (int r = 0; r < 4; ++r) {
      int node = node0 + quad * 4 + r;
      if (node >= n) break;
      float l0 = acc[0][r] + bias[0];
      float l1 = acc[1][r] + bias[1];
      float l2 = acc[2][r] + bias[2];
      float l3 = acc[3][r] + bias[3];
      float mx = fmaxf(fmaxf(l0, l1), fmaxf(l2, l3));
#pragma unroll
      for (int off = 1; off <= 8; off <<= 1) mx = fmaxf(mx, __shfl_xor(mx, off, 64));
      float s = expf(l0 - mx) + expf(l1 - mx) + expf(l2 - mx) + expf(l3 - mx);
#pragma unroll
      for (int off = 1; off <= 8; off <<= 1) s += __shfl_xor(s, off, 64);
      float ls = logf(s);
      size_t rb = (size_t)node * 64 + m;
      out[rb + 0]  = l0 - mx - ls;
      out[rb + 16] = l1 - mx - ls;
      out[rb + 32] = l2 - mx - ls;
      out[rb + 48] = l3 - mx - ls;
    }
  }
}

extern "C" void kernel_launch(void* const* d_in, const int* in_sizes, int n_in,
                              void* d_out, int out_size, void* d_ws, size_t ws_size,
                              hipStream_t stream) {
  const float* x    = (const float*)d_in[0];
  const int*   ei   = (const int*)d_in[1];
  const float* W1l  = (const float*)d_in[2];
  const float* b1l  = (const float*)d_in[3];
  const float* W1r  = (const float*)d_in[4];
  const float* W2l  = (const float*)d_in[5];
  const float* b2l  = (const float*)d_in[6];
  const float* W2r  = (const float*)d_in[7];
  const float* Wout = (const float*)d_in[8];
  const float* bout = (const float*)d_in[9];
  int N = in_sizes[0] / 64;
  int E = in_sizes[1] / 2;
  int NB = (N + 127) >> 7;  // 128-node buckets; NB=782 <= NBPAD

  char* p = (char*)d_ws;
  auto carve = [&](size_t bytes) {
    char* r = p;
    p += (bytes + 255) & ~(size_t)255;
    return r;
  };
  int* cellcnt       = (int*)carve((size_t)NBINA * NBPAD * 4);   // 1 MB
  int* cnt           = (int*)carve((size_t)NB * 128 * 4);        // padded
  int* colp          = (int*)carve((size_t)NB * 128 * 64 * 4);   // padded
  unsigned short* y  = (unsigned short*)carve((size_t)N * 64 * 2);
  unsigned short* z  = (unsigned short*)carve((size_t)N * 64 * 2);
  unsigned int* bucketData = (unsigned int*)carve((size_t)NB * NBINA * CAPC * 4);  // 25.6 MB

  int aggr_blocks = (N + 15) / 16;  // 4 nodes/wave, 4 waves/block
  // single-pass binning || layer-1 transform (independent -> one fused launch)
  k_binA_xf<<<NBINA + XFB, TB, 0, stream>>>(ei, E, cellcnt, bucketData, NB,
                                            x, W1l, W1r, b1l, y, z, N);
  k_binB<<<NB, TB, 0, stream>>>(bucketData, cellcnt, colp, cnt);
  k_aggr<<<aggr_blocks, TB, 0, stream>>>(y, cnt, colp, z, N);  // z = h1 (bf16)
  // layer 2 (reads z in place; y buffer reused)
  k_xform_b16<<<XFB, TB, 0, stream>>>(z, W2l, W2r, b2l, y, z, N);
  k_aggr<<<aggr_blocks, TB, 0, stream>>>(y, cnt, colp, z, N);  // z = h2 (bf16)
  // head
  k_out<<<XFB, TB, 0, stream>>>(z, Wout, bout, (float*)d_out, N);
}